// Round 2
// baseline (14451.013 us; speedup 1.0000x reference)
//
#include <hip/hip_runtime.h>
#include <stdint.h>

#define T_STEPS 512

typedef short short8 __attribute__((ext_vector_type(8)));
typedef float floatx4 __attribute__((ext_vector_type(4)));

__device__ __forceinline__ unsigned short f2bf(float f) {
  unsigned int u = __builtin_bit_cast(unsigned int, f);
  u = u + 0x7fff + ((u >> 16) & 1);   // round-to-nearest-even
  return (unsigned short)(u >> 16);
}
__device__ __forceinline__ float bf2f(unsigned short s) {
  unsigned int u = ((unsigned int)s) << 16;
  return __builtin_bit_cast(float, u);
}
__device__ __forceinline__ float sigm(float x) { return 1.f / (1.f + __expf(-x)); }
__device__ __forceinline__ float tanh_fast(float x) {
  float e2 = __expf(2.f * x);           // overflow -> inf -> 1; underflow -> 0 -> -1
  return 1.f - 2.f / (e2 + 1.f);
}

// async global->LDS, 16B per lane. LDS dest must be wave-uniform base + lane*16.
__device__ __forceinline__ void gload16(const void* g, const void* l) {
  __builtin_amdgcn_global_load_lds((const __attribute__((address_space(1))) unsigned int*)g,
                                   (__attribute__((address_space(3))) unsigned int*)l,
                                   16, 0, 0);
}

// ---------------------------------------------------------------------------
// Packing kernels
// ---------------------------------------------------------------------------
__global__ void pack_bf(const float* __restrict__ in, unsigned short* __restrict__ out, int n) {
  int i = blockIdx.x * 256 + threadIdx.x;
  if (i < n) out[i] = f2bf(in[i]);
}

// transpose-pack: dst[e][k] (bf16, row len dldk) = src[k*srcStride + e]
// grid: (Ncols/32, Krows/32), block (32,8)
__global__ void packT(const float* __restrict__ src, int srcStride,
                      unsigned short* __restrict__ dst, int dldk, int koff) {
  __shared__ float tile[32][33];
  int tx = threadIdx.x, ty = threadIdx.y;
  int e0 = blockIdx.x * 32, k0 = blockIdx.y * 32;
#pragma unroll
  for (int i = 0; i < 4; ++i)
    tile[ty + 8 * i][tx] = src[(size_t)(k0 + ty + 8 * i) * srcStride + e0 + tx];
  __syncthreads();
#pragma unroll
  for (int i = 0; i < 4; ++i)
    dst[(size_t)(e0 + ty + 8 * i) * dldk + koff + k0 + tx] = f2bf(tile[tx][ty + 8 * i]);
}

__global__ void init_h(const float* __restrict__ ph, float* __restrict__ hf,
                       unsigned short* __restrict__ hb) {
  int i = blockIdx.x * 256 + threadIdx.x;
  if (i < 32 * 1024) { float v = ph[i]; hf[i] = v; hb[i] = f2bf(v); }
}

__global__ void sentinel(float* out, float v) { out[0] = v; }

// ---------------------------------------------------------------------------
// Big MFMA GEMM: C(M x Nn) = epilogue( [A0|A1](M x K, bf16) @ BT^T + bias )
// BT is N x K row-major bf16. Tile 128x128, BK=32, 4 waves (2x2), 4x4 frags.
// EPI 0: gates   -> out_bf = bf16(acc + bias[col])           (Nn = 3072)
// EPI 1: grd     -> sigmoid; col<1024 -> ud (f32); col>=1024 -> rdx = bf16(rd*x)
// EPI 2: out     -> hcd = tanh(acc+bias); out = x + ud*(hcd - x)   (ud aliases outf!)
// ---------------------------------------------------------------------------
template <int EPI>
__global__ __launch_bounds__(256) void gemm_bt(
    const unsigned short* __restrict__ A0, const unsigned short* __restrict__ A1,
    const unsigned short* __restrict__ BT,
    int M, int Nn, int K, int KA0,
    const float* __restrict__ bias,
    unsigned short* __restrict__ out_bf,
    const float* __restrict__ xf,
    float* __restrict__ ud,
    unsigned short* __restrict__ rdx,
    float* __restrict__ outf) {
  __shared__ unsigned short At[128 * 32];
  __shared__ unsigned short Bt[128 * 32];
  const int tid = threadIdx.x;
  const int lane = tid & 63, wave = tid >> 6;
  const int wm = wave >> 1, wn = wave & 1;
  const int m0 = blockIdx.y * 128, n0 = blockIdx.x * 128;
  const int lr = lane & 15, lk = (lane >> 4) * 8;
  floatx4 acc[4][4] = {};

  for (int k0 = 0; k0 < K; k0 += 32) {
    const unsigned short* As;
    int kk;
    if (k0 < KA0) { As = A0 + (size_t)m0 * KA0 + k0; kk = KA0; }
    else          { As = A1 + (size_t)m0 * (K - KA0) + (k0 - KA0); kk = K - KA0; }
#pragma unroll
    for (int j = 0; j < 2; ++j) {
      int chunk = j * 256 + tid;
      int row = chunk >> 2, kc = chunk & 3;
      gload16(As + (size_t)row * kk + kc * 8, (const char*)At + chunk * 16);
    }
    const unsigned short* Bs = BT + (size_t)n0 * K + k0;
#pragma unroll
    for (int j = 0; j < 2; ++j) {
      int chunk = j * 256 + tid;
      int row = chunk >> 2, kc = chunk & 3;
      gload16(Bs + (size_t)row * K + kc * 8, (const char*)Bt + chunk * 16);
    }
    __syncthreads();
    short8 a[4], b[4];
#pragma unroll
    for (int i = 0; i < 4; ++i) a[i] = *(const short8*)(At + (wm * 64 + i * 16 + lr) * 32 + lk);
#pragma unroll
    for (int i = 0; i < 4; ++i) b[i] = *(const short8*)(Bt + (wn * 64 + i * 16 + lr) * 32 + lk);
#pragma unroll
    for (int i = 0; i < 4; ++i)
#pragma unroll
      for (int j = 0; j < 4; ++j)
        acc[i][j] = __builtin_amdgcn_mfma_f32_16x16x32_bf16(a[i], b[j], acc[i][j], 0, 0, 0);
    __syncthreads();
  }

#pragma unroll
  for (int i = 0; i < 4; ++i) {
#pragma unroll
    for (int j = 0; j < 4; ++j) {
      int col = n0 + wn * 64 + j * 16 + lr;
#pragma unroll
      for (int r = 0; r < 4; ++r) {
        int row = m0 + wm * 64 + i * 16 + (lane >> 4) * 4 + r;
        float v = acc[i][j][r];
        if constexpr (EPI == 0) {
          out_bf[(size_t)row * Nn + col] = f2bf(v + bias[col]);
        } else if constexpr (EPI == 1) {
          float s = sigm(v + bias[col]);
          if (col < 1024) {
            ud[(size_t)row * 1024 + col] = s;
          } else {
            size_t ix = (size_t)row * 1024 + (col - 1024);
            rdx[ix] = f2bf(s * xf[ix]);
          }
        } else {
          float hc = tanh_fast(v + bias[col]);
          size_t ix = (size_t)row * 1024 + col;
          float xv = xf[ix];
          outf[ix] = xv + ud[ix] * (hc - xv);   // ud aliases outf at same ix: safe
        }
      }
    }
  }
}

// ---------------------------------------------------------------------------
// Scan step kernels. M=32 (batch), MFMA 16x16x32, 4 waves x 16 cols = 64 cols/block.
// S1: gg = sigmoid(gates[:,t,:2048] + h @ Whtg); col<1024 -> u (f32); else rh=bf16(r*h)
// S2: hc = tanh(gates[:,t,2048:] + rh @ Whtc); h' = h + u*(hc-h); record ht, last_ht
// ---------------------------------------------------------------------------
__global__ __launch_bounds__(256) void scan_s1(
    const unsigned short* __restrict__ hb, const float* __restrict__ hf,
    const unsigned short* __restrict__ WgT, const unsigned short* __restrict__ gates,
    float* __restrict__ ubuf, unsigned short* __restrict__ rh, int t) {
  __shared__ unsigned short At[32 * 64];
  __shared__ unsigned short Bt[64 * 64];
  const int tid = threadIdx.x, lane = tid & 63, w = tid >> 6;
  const int n0b = blockIdx.x * 64;
  const int lr = lane & 15, lk = (lane >> 4) * 8;
  floatx4 acc[2] = {};
  for (int k0 = 0; k0 < 1024; k0 += 64) {
    {
      int row = tid >> 3, kc = tid & 7;
      gload16(hb + (size_t)row * 1024 + k0 + kc * 8, (const char*)At + tid * 16);
    }
#pragma unroll
    for (int j = 0; j < 2; ++j) {
      int chunk = j * 256 + tid;
      int row = chunk >> 3, kc = chunk & 7;
      gload16(WgT + (size_t)(n0b + row) * 1024 + k0 + kc * 8, (const char*)Bt + chunk * 16);
    }
    __syncthreads();
#pragma unroll
    for (int ks = 0; ks < 2; ++ks) {
      short8 b = *(const short8*)(Bt + (w * 16 + lr) * 64 + ks * 32 + lk);
#pragma unroll
      for (int mi = 0; mi < 2; ++mi) {
        short8 a = *(const short8*)(At + (mi * 16 + lr) * 64 + ks * 32 + lk);
        acc[mi] = __builtin_amdgcn_mfma_f32_16x16x32_bf16(a, b, acc[mi], 0, 0, 0);
      }
    }
    __syncthreads();
  }
#pragma unroll
  for (int mi = 0; mi < 2; ++mi) {
    int col = n0b + w * 16 + lr;
#pragma unroll
    for (int r = 0; r < 4; ++r) {
      int row = mi * 16 + (lane >> 4) * 4 + r;
      float g = bf2f(gates[((size_t)row * T_STEPS + t) * 3072 + col]);
      float s = sigm(acc[mi][r] + g);
      if (col < 1024) {
        ubuf[row * 1024 + col] = s;
      } else {
        int ix = row * 1024 + col - 1024;
        rh[ix] = f2bf(s * hf[ix]);
      }
    }
  }
}

__global__ __launch_bounds__(256) void scan_s2(
    const unsigned short* __restrict__ rh, const unsigned short* __restrict__ WcT,
    const unsigned short* __restrict__ gates, const float* __restrict__ ubuf,
    float* __restrict__ hf, unsigned short* __restrict__ hb,
    unsigned short* __restrict__ htb, float* __restrict__ lastht, int t) {
  __shared__ unsigned short At[32 * 64];
  __shared__ unsigned short Bt[64 * 64];
  const int tid = threadIdx.x, lane = tid & 63, w = tid >> 6;
  const int n0b = blockIdx.x * 64;
  const int lr = lane & 15, lk = (lane >> 4) * 8;
  floatx4 acc[2] = {};
  for (int k0 = 0; k0 < 1024; k0 += 64) {
    {
      int row = tid >> 3, kc = tid & 7;
      gload16(rh + (size_t)row * 1024 + k0 + kc * 8, (const char*)At + tid * 16);
    }
#pragma unroll
    for (int j = 0; j < 2; ++j) {
      int chunk = j * 256 + tid;
      int row = chunk >> 3, kc = chunk & 7;
      gload16(WcT + (size_t)(n0b + row) * 1024 + k0 + kc * 8, (const char*)Bt + chunk * 16);
    }
    __syncthreads();
#pragma unroll
    for (int ks = 0; ks < 2; ++ks) {
      short8 b = *(const short8*)(Bt + (w * 16 + lr) * 64 + ks * 32 + lk);
#pragma unroll
      for (int mi = 0; mi < 2; ++mi) {
        short8 a = *(const short8*)(At + (mi * 16 + lr) * 64 + ks * 32 + lk);
        acc[mi] = __builtin_amdgcn_mfma_f32_16x16x32_bf16(a, b, acc[mi], 0, 0, 0);
      }
    }
    __syncthreads();
  }
#pragma unroll
  for (int mi = 0; mi < 2; ++mi) {
    int col = n0b + w * 16 + lr;
#pragma unroll
    for (int r = 0; r < 4; ++r) {
      int row = mi * 16 + (lane >> 4) * 4 + r;
      int ix = row * 1024 + col;
      float g = bf2f(gates[((size_t)row * T_STEPS + t) * 3072 + 2048 + col]);
      float hc = tanh_fast(acc[mi][r] + g);
      float ho = hf[ix];
      float un = ubuf[ix];
      float hn = ho + un * (hc - ho);
      hf[ix] = hn;
      unsigned short hv = f2bf(hn);
      hb[ix] = hv;
      htb[((size_t)row * T_STEPS + t) * 1024 + col] = hv;
      if (t == T_STEPS - 1) lastht[ix] = hn;
    }
  }
}

// ---------------------------------------------------------------------------
extern "C" void kernel_launch(void* const* d_in, const int* in_sizes, int n_in,
                              void* d_out, int out_size, void* d_ws, size_t ws_size,
                              hipStream_t stream) {
  const float* x    = (const float*)d_in[0];   // (32,512,1024)
  const float* ph   = (const float*)d_in[1];   // (32,1024)
  const float* wgt  = (const float*)d_in[2];   // (2048,6144)
  const float* bias = (const float*)d_in[3];   // (6144,)
  float* out = (float*)d_out;                  // h (16777216) + last_ht (32768)

  // ---- workspace layout (193.3 MB total) ----
  const size_t SZ_XBF   = (size_t)16384 * 1024 * 2;   // 33.5 MB
  const size_t SZ_GATES = (size_t)16384 * 3072 * 2;   // 100.7 MB (rdx aliases here)
  const size_t SZ_HTB   = (size_t)16384 * 1024 * 2;   // 33.5 MB
  const size_t SZ_W     = ((size_t)3072 * 1024 + (size_t)2048 * 2048 +
                           (size_t)1024 * 2048 + (size_t)2048 * 1024 +
                           (size_t)1024 * 1024) * 2;  // 25.2 MB
  const size_t SZ_SMALL = (size_t)(32 * 1024) * (4 + 4 + 2 + 2); // ubuf,hf,hb,rh
  const size_t REQUIRED = SZ_XBF + SZ_GATES + SZ_HTB + SZ_W + SZ_SMALL;

  if (ws_size < REQUIRED) {
    // Probe: report the actual workspace budget through the absmax failure.
    sentinel<<<1, 1, 0, stream>>>(out, (float)ws_size);
    return;
  }

  char* p = (char*)d_ws;
  unsigned short* xbf   = (unsigned short*)p; p += SZ_XBF;
  unsigned short* gates = (unsigned short*)p;
  unsigned short* rdx   = (unsigned short*)p; p += SZ_GATES;  // rdx aliases gates (dead after scan)
  unsigned short* htb   = (unsigned short*)p; p += SZ_HTB;
  unsigned short* wxtT  = (unsigned short*)p; p += (size_t)3072 * 1024 * 2;
  unsigned short* w1T   = (unsigned short*)p; p += (size_t)2048 * 2048 * 2;
  unsigned short* w2T   = (unsigned short*)p; p += (size_t)1024 * 2048 * 2;
  unsigned short* wgT   = (unsigned short*)p; p += (size_t)2048 * 1024 * 2;
  unsigned short* wcT   = (unsigned short*)p; p += (size_t)1024 * 1024 * 2;
  float* ubuf           = (float*)p;          p += (size_t)32 * 1024 * 4;
  float* hf             = (float*)p;          p += (size_t)32 * 1024 * 4;
  unsigned short* hb    = (unsigned short*)p; p += (size_t)32 * 1024 * 2;
  unsigned short* rh    = (unsigned short*)p; p += (size_t)32 * 1024 * 2;
  float* udf = out;  // ud aliases d_out's h region (exactly 16777216 floats); see gemm epilogues

  dim3 tb(32, 8);

  // pack inputs
  pack_bf<<<65536, 256, 0, stream>>>(x, xbf, 16384 * 1024);
  // WxtT (3072 x 1024) <- weight[:1024, :3072]
  packT<<<dim3(96, 32), tb, 0, stream>>>(wgt, 6144, wxtT, 1024, 0);
  // W1T (2048 x 2048) <- weight[:, 3072:5120] (rows: Wxd then Whd)
  packT<<<dim3(64, 64), tb, 0, stream>>>(wgt + 3072, 6144, w1T, 2048, 0);
  // W2T (1024 x 2048): k<1024 <- Whd[:,2048:] (weight rows 1024+), k>=1024 <- Wxd[:,2048:]
  packT<<<dim3(32, 32), tb, 0, stream>>>(wgt + (size_t)1024 * 6144 + 5120, 6144, w2T, 2048, 0);
  packT<<<dim3(32, 32), tb, 0, stream>>>(wgt + 5120, 6144, w2T, 2048, 1024);
  // WhtgT (2048 x 1024) <- weight[1024:, :2048]
  packT<<<dim3(64, 32), tb, 0, stream>>>(wgt + (size_t)1024 * 6144, 6144, wgT, 1024, 0);
  // WhtcT (1024 x 1024) <- weight[1024:, 2048:3072]
  packT<<<dim3(32, 32), tb, 0, stream>>>(wgt + (size_t)1024 * 6144 + 2048, 6144, wcT, 1024, 0);

  // gates = bf16(x @ Wxt + bt)
  gemm_bt<0><<<dim3(24, 128), 256, 0, stream>>>(xbf, xbf, wxtT, 16384, 3072, 1024, 1024,
                                                bias, gates, nullptr, nullptr, nullptr, nullptr);

  init_h<<<128, 256, 0, stream>>>(ph, hf, hb);

  for (int t = 0; t < T_STEPS; ++t) {
    scan_s1<<<32, 256, 0, stream>>>(hb, hf, wgT, gates, ubuf, rh, t);
    scan_s2<<<16, 256, 0, stream>>>(rh, wcT, gates, ubuf, hf, hb, htb,
                                    out + (size_t)16384 * 1024, t);
  }

  // grd = sigmoid(bd[:2048] + [x|ht] @ W1T^T) -> ud (f32, in d_out), rdx = bf16(rd*x)
  gemm_bt<1><<<dim3(16, 128), 256, 0, stream>>>(xbf, htb, w1T, 16384, 2048, 2048, 1024,
                                                bias + 3072, nullptr, x, udf, rdx, nullptr);
  // h = x + ud*(tanh(bd[2048:] + [ht|rdx] @ W2T^T) - x)
  gemm_bt<2><<<dim3(8, 128), 256, 0, stream>>>(htb, rdx, w2T, 16384, 1024, 2048, 1024,
                                               bias + 5120, nullptr, x, udf, nullptr, out);
}

// Round 3
// 4014.518 us; speedup vs baseline: 3.5997x; 3.5997x over previous
//
#include <hip/hip_runtime.h>
#include <stdint.h>

#define T_STEPS 512
#define GBLK 64   // blocks per scan group

typedef short short8 __attribute__((ext_vector_type(8)));
typedef float floatx4 __attribute__((ext_vector_type(4)));

__device__ __forceinline__ unsigned short f2bf(float f) {
  unsigned int u = __builtin_bit_cast(unsigned int, f);
  u = u + 0x7fff + ((u >> 16) & 1);   // round-to-nearest-even
  return (unsigned short)(u >> 16);
}
__device__ __forceinline__ float bf2f(unsigned short s) {
  unsigned int u = ((unsigned int)s) << 16;
  return __builtin_bit_cast(float, u);
}
__device__ __forceinline__ float sigm(float x) { return 1.f / (1.f + __expf(-x)); }
__device__ __forceinline__ float tanh_fast(float x) {
  float e2 = __expf(2.f * x);
  return 1.f - 2.f / (e2 + 1.f);
}

__device__ __forceinline__ void gload16(const void* g, const void* l) {
  __builtin_amdgcn_global_load_lds((const __attribute__((address_space(1))) unsigned int*)g,
                                   (__attribute__((address_space(3))) unsigned int*)l,
                                   16, 0, 0);
}

// ---------------------------------------------------------------------------
__global__ void pack_bf(const float* __restrict__ in, unsigned short* __restrict__ out, int n) {
  int i = blockIdx.x * 256 + threadIdx.x;
  if (i < n) out[i] = f2bf(in[i]);
}

__global__ void packT(const float* __restrict__ src, int srcStride,
                      unsigned short* __restrict__ dst, int dldk, int koff) {
  __shared__ float tile[32][33];
  int tx = threadIdx.x, ty = threadIdx.y;
  int e0 = blockIdx.x * 32, k0 = blockIdx.y * 32;
#pragma unroll
  for (int i = 0; i < 4; ++i)
    tile[ty + 8 * i][tx] = src[(size_t)(k0 + ty + 8 * i) * srcStride + e0 + tx];
  __syncthreads();
#pragma unroll
  for (int i = 0; i < 4; ++i)
    dst[(size_t)(e0 + ty + 8 * i) * dldk + koff + k0 + tx] = f2bf(tile[tx][ty + 8 * i]);
}

__global__ void sentinel(float* out, float v) { out[0] = v; }

// ---------------------------------------------------------------------------
// Big MFMA GEMM (unchanged from round 2, verified correct)
// ---------------------------------------------------------------------------
template <int EPI>
__global__ __launch_bounds__(256) void gemm_bt(
    const unsigned short* __restrict__ A0, const unsigned short* __restrict__ A1,
    const unsigned short* __restrict__ BT,
    int M, int Nn, int K, int KA0,
    const float* __restrict__ bias,
    unsigned short* __restrict__ out_bf,
    const float* __restrict__ xf,
    float* __restrict__ ud,
    unsigned short* __restrict__ rdx,
    float* __restrict__ outf) {
  __shared__ unsigned short At[128 * 32];
  __shared__ unsigned short Bt[128 * 32];
  const int tid = threadIdx.x;
  const int lane = tid & 63, wave = tid >> 6;
  const int wm = wave >> 1, wn = wave & 1;
  const int m0 = blockIdx.y * 128, n0 = blockIdx.x * 128;
  const int lr = lane & 15, lk = (lane >> 4) * 8;
  floatx4 acc[4][4] = {};

  for (int k0 = 0; k0 < K; k0 += 32) {
    const unsigned short* As;
    int kk;
    if (k0 < KA0) { As = A0 + (size_t)m0 * KA0 + k0; kk = KA0; }
    else          { As = A1 + (size_t)m0 * (K - KA0) + (k0 - KA0); kk = K - KA0; }
#pragma unroll
    for (int j = 0; j < 2; ++j) {
      int chunk = j * 256 + tid;
      int row = chunk >> 2, kc = chunk & 3;
      gload16(As + (size_t)row * kk + kc * 8, (const char*)At + chunk * 16);
    }
    const unsigned short* Bs = BT + (size_t)n0 * K + k0;
#pragma unroll
    for (int j = 0; j < 2; ++j) {
      int chunk = j * 256 + tid;
      int row = chunk >> 2, kc = chunk & 3;
      gload16(Bs + (size_t)row * K + kc * 8, (const char*)Bt + chunk * 16);
    }
    __syncthreads();
    short8 a[4], b[4];
#pragma unroll
    for (int i = 0; i < 4; ++i) a[i] = *(const short8*)(At + (wm * 64 + i * 16 + lr) * 32 + lk);
#pragma unroll
    for (int i = 0; i < 4; ++i) b[i] = *(const short8*)(Bt + (wn * 64 + i * 16 + lr) * 32 + lk);
#pragma unroll
    for (int i = 0; i < 4; ++i)
#pragma unroll
      for (int j = 0; j < 4; ++j)
        acc[i][j] = __builtin_amdgcn_mfma_f32_16x16x32_bf16(a[i], b[j], acc[i][j], 0, 0, 0);
    __syncthreads();
  }

#pragma unroll
  for (int i = 0; i < 4; ++i) {
#pragma unroll
    for (int j = 0; j < 4; ++j) {
      int col = n0 + wn * 64 + j * 16 + lr;
#pragma unroll
      for (int r = 0; r < 4; ++r) {
        int row = m0 + wm * 64 + i * 16 + (lane >> 4) * 4 + r;
        float v = acc[i][j][r];
        if constexpr (EPI == 0) {
          out_bf[(size_t)row * Nn + col] = f2bf(v + bias[col]);
        } else if constexpr (EPI == 1) {
          float s = sigm(v + bias[col]);
          if (col < 1024) {
            ud[(size_t)row * 1024 + col] = s;
          } else {
            size_t ix = (size_t)row * 1024 + (col - 1024);
            rdx[ix] = f2bf(s * xf[ix]);
          }
        } else {
          float hc = tanh_fast(v + bias[col]);
          size_t ix = (size_t)row * 1024 + col;
          float xv = xf[ix];
          outf[ix] = xv + ud[ix] * (hc - xv);   // ud aliases outf at same ix: safe
        }
      }
    }
  }
}

// ---------------------------------------------------------------------------
// Persistent scan. 128 blocks = 2 groups x 64. Group g owns batch rows
// [g*16, g*16+16). Block b owns output cols [b*16, b*16+16) (u, r, hc all at
// the same cols -> u and h_f32 state stay block-local in LDS all 512 steps).
// Weights LDS-resident (XOR-swizzled). Per step: stage h -> phase A (u,r;
// write rh agent-coherent) -> barrier -> stage rh -> phase B (hc; update h;
// write hb agent-coherent) -> barrier.
// ---------------------------------------------------------------------------
__device__ __forceinline__ void group_barrier(unsigned int* c) {
  __syncthreads();                       // drains vmcnt: prior stores at L2/LLC
  if (threadIdx.x == 0) {
    __hip_atomic_fetch_add(c, 1u, __ATOMIC_RELAXED, __HIP_MEMORY_SCOPE_AGENT);
    int spins = 0;
    while (__hip_atomic_load(c, __ATOMIC_RELAXED, __HIP_MEMORY_SCOPE_AGENT) < (unsigned)GBLK) {
      if (++spins > (1 << 27)) break;    // safety valve: wrong answer > hang
      if (spins > 64) __builtin_amdgcn_s_sleep(2);
    }
    (void)__hip_atomic_load(c, __ATOMIC_ACQUIRE, __HIP_MEMORY_SCOPE_AGENT); // L1/L2 inv
  }
  __syncthreads();
}

__global__ __launch_bounds__(256, 1) void scan_pk(
    const unsigned short* __restrict__ wgT,   // [2048][1024]
    const unsigned short* __restrict__ wcT,   // [1024][1024]
    const unsigned short* __restrict__ gates, // [32*512][3072]
    const float* __restrict__ ph,             // [32][1024]
    unsigned short* __restrict__ hb,          // [32][1024] broadcast h (bf16)
    unsigned short* __restrict__ rhbuf,       // [32][1024] broadcast r*h (bf16)
    unsigned short* __restrict__ htb,         // [32*512][1024]
    float* __restrict__ lastht,               // [32][1024]
    unsigned int* __restrict__ bars)          // [2][1026]
{
  __shared__ unsigned short Wg[32 * 1024];    // rows 0-15: Whtg u-cols, 16-31: r-cols
  __shared__ unsigned short Wc[16 * 1024];
  __shared__ unsigned short Stg[16 * 1024];   // h (phase A) / rh (phase B) stage
  __shared__ float Part[4][16][17];
  __shared__ float Ubuf[16][16];
  __shared__ float Hloc[16][16];              // f32 running h at this block's cols
  __shared__ unsigned short Gbuf[3][16][16];  // gate slices: u, r, c

  const int tid = threadIdx.x;
  const int lane = tid & 63, wave = tid >> 6;
  const int lr = lane & 15, lq = lane >> 4;
  const int bid = blockIdx.x;
  const int g = bid >> 6, b = bid & 63;
  const int row0 = g * 16, col0 = b * 16;
  unsigned int* bar = bars + g * 1026;

  // ---- setup: stage weights into LDS (source pre-swizzled: chunk ^= row&7) ----
#pragma unroll
  for (int i = 0; i < 16; ++i) {
    int p = i * 256 + tid;                // chunk in Wg (4096 total)
    int wr = p >> 7, kcp = p & 127;
    int kc = kcp ^ (wr & 7);
    int grow = (wr < 16) ? (col0 + wr) : (1024 + col0 + (wr - 16));
    gload16(wgT + (size_t)grow * 1024 + kc * 8, (const char*)Wg + p * 16);
  }
#pragma unroll
  for (int i = 0; i < 8; ++i) {
    int p = i * 256 + tid;                // chunk in Wc (2048 total)
    int wr = p >> 7, kcp = p & 127;
    int kc = kcp ^ (wr & 7);
    gload16(wcT + (size_t)(col0 + wr) * 1024 + kc * 8, (const char*)Wc + p * 16);
  }
  {
    int r = tid >> 4, c = tid & 15;
    float v = ph[(size_t)(row0 + r) * 1024 + col0 + c];
    Hloc[r][c] = v;
    __hip_atomic_store(&hb[(size_t)(row0 + r) * 1024 + col0 + c], f2bf(v),
                       __ATOMIC_RELAXED, __HIP_MEMORY_SCOPE_AGENT);
  }
  group_barrier(&bar[0]);

  for (int t = 0; t < T_STEPS; ++t) {
    // ---- stage h into Stg (swizzled via source permute) + gate prefetch ----
#pragma unroll
    for (int i = 0; i < 8; ++i) {
      int p = i * 256 + tid;
      int r = p >> 7, kcp = p & 127;
      int kc = kcp ^ (r & 7);
      gload16(hb + (size_t)(row0 + r) * 1024 + kc * 8, (const char*)Stg + p * 16);
    }
    if (tid < 96) {
      int s = tid >> 5, row = (tid >> 1) & 15, half = tid & 1;
      int gcol = (s == 0) ? col0 : (s == 1) ? (1024 + col0) : (2048 + col0);
      gload16(gates + ((size_t)(row0 + row) * T_STEPS + t) * 3072 + gcol + half * 8,
              (const char*)&Gbuf[0][0][0] + tid * 16);
    }
    __syncthreads();

    // ---- phase A: 16x32 = h @ Whtg[cols]; waves: wc = col half, wk = K half
    {
      const int wc = wave & 1, wk = wave >> 1;
      floatx4 acc = {};
#pragma unroll
      for (int ks = 0; ks < 16; ++ks) {
        int kci = (wk * 16 + ks) * 4 + lq;
        int sw = kci ^ (lr & 7);
        short8 av = *(const short8*)(Stg + lr * 1024 + sw * 8);
        short8 bv = *(const short8*)(Wg + (wc * 16 + lr) * 1024 + sw * 8);
        acc = __builtin_amdgcn_mfma_f32_16x16x32_bf16(av, bv, acc, 0, 0, 0);
      }
      const int tix = wk * 2 + wc;
#pragma unroll
      for (int r = 0; r < 4; ++r) Part[tix][lq * 4 + r][lr] = acc[r];
    }
    __syncthreads();

#pragma unroll
    for (int e = 0; e < 2; ++e) {
      int o = e * 256 + tid;
      int row = o >> 5, col = o & 31;
      int wcc = col >> 4, c = col & 15;
      float sum = Part[wcc][row][c] + Part[2 + wcc][row][c];
      float sv = sigm(sum + bf2f(Gbuf[wcc][row][c]));
      if (wcc == 0) {
        Ubuf[row][c] = sv;
      } else {
        unsigned short rv = f2bf(sv * Hloc[row][c]);
        __hip_atomic_store(&rhbuf[(size_t)(row0 + row) * 1024 + col0 + c], rv,
                           __ATOMIC_RELAXED, __HIP_MEMORY_SCOPE_AGENT);
      }
    }
    group_barrier(&bar[1 + 2 * t]);

    // ---- stage rh ----
#pragma unroll
    for (int i = 0; i < 8; ++i) {
      int p = i * 256 + tid;
      int r = p >> 7, kcp = p & 127;
      int kc = kcp ^ (r & 7);
      gload16(rhbuf + (size_t)(row0 + r) * 1024 + kc * 8, (const char*)Stg + p * 16);
    }
    __syncthreads();

    // ---- phase B: 16x16 = rh @ Whtc[cols]; waves split K 4-way
    {
      floatx4 acc = {};
#pragma unroll
      for (int ks = 0; ks < 8; ++ks) {
        int kci = (wave * 8 + ks) * 4 + lq;
        int sw = kci ^ (lr & 7);
        short8 av = *(const short8*)(Stg + lr * 1024 + sw * 8);
        short8 bv = *(const short8*)(Wc + lr * 1024 + sw * 8);
        acc = __builtin_amdgcn_mfma_f32_16x16x32_bf16(av, bv, acc, 0, 0, 0);
      }
#pragma unroll
      for (int r = 0; r < 4; ++r) Part[wave][lq * 4 + r][lr] = acc[r];
    }
    __syncthreads();

    {
      int row = tid >> 4, c = tid & 15;
      float sum = Part[0][row][c] + Part[1][row][c] + Part[2][row][c] + Part[3][row][c];
      float hc = tanh_fast(sum + bf2f(Gbuf[2][row][c]));
      float h = Hloc[row][c], u = Ubuf[row][c];
      float hn = h + u * (hc - h);
      Hloc[row][c] = hn;
      unsigned short hv = f2bf(hn);
      __hip_atomic_store(&hb[(size_t)(row0 + row) * 1024 + col0 + c], hv,
                         __ATOMIC_RELAXED, __HIP_MEMORY_SCOPE_AGENT);
      htb[((size_t)(row0 + row) * T_STEPS + t) * 1024 + col0 + c] = hv;
      if (t == T_STEPS - 1) lastht[(size_t)(row0 + row) * 1024 + col0 + c] = hn;
    }
    group_barrier(&bar[2 + 2 * t]);
  }
}

// ---------------------------------------------------------------------------
extern "C" void kernel_launch(void* const* d_in, const int* in_sizes, int n_in,
                              void* d_out, int out_size, void* d_ws, size_t ws_size,
                              hipStream_t stream) {
  const float* x    = (const float*)d_in[0];   // (32,512,1024)
  const float* ph   = (const float*)d_in[1];   // (32,1024)
  const float* wgt  = (const float*)d_in[2];   // (2048,6144)
  const float* bias = (const float*)d_in[3];   // (6144,)
  float* out = (float*)d_out;                  // h (16777216) + last_ht (32768)

  const size_t SZ_BARS  = 16384;                      // 2*1026*4 used
  const size_t SZ_XBF   = (size_t)16384 * 1024 * 2;
  const size_t SZ_GATES = (size_t)16384 * 3072 * 2;   // rdx aliases here after scan
  const size_t SZ_HTB   = (size_t)16384 * 1024 * 2;
  const size_t SZ_W     = ((size_t)3072 * 1024 + (size_t)2048 * 2048 +
                           (size_t)1024 * 2048 + (size_t)2048 * 1024 +
                           (size_t)1024 * 1024) * 2;
  const size_t SZ_SMALL = (size_t)(32 * 1024) * (2 + 2); // hb, rhbuf
  const size_t REQUIRED = SZ_BARS + SZ_XBF + SZ_GATES + SZ_HTB + SZ_W + SZ_SMALL;

  if (ws_size < REQUIRED) {
    sentinel<<<1, 1, 0, stream>>>(out, (float)ws_size);
    return;
  }

  char* p = (char*)d_ws;
  unsigned int* bars    = (unsigned int*)p;   p += SZ_BARS;
  unsigned short* xbf   = (unsigned short*)p; p += SZ_XBF;
  unsigned short* gates = (unsigned short*)p;
  unsigned short* rdx   = (unsigned short*)p; p += SZ_GATES;
  unsigned short* htb   = (unsigned short*)p; p += SZ_HTB;
  unsigned short* wxtT  = (unsigned short*)p; p += (size_t)3072 * 1024 * 2;
  unsigned short* w1T   = (unsigned short*)p; p += (size_t)2048 * 2048 * 2;
  unsigned short* w2T   = (unsigned short*)p; p += (size_t)1024 * 2048 * 2;
  unsigned short* wgT   = (unsigned short*)p; p += (size_t)2048 * 1024 * 2;
  unsigned short* wcT   = (unsigned short*)p; p += (size_t)1024 * 1024 * 2;
  unsigned short* hb    = (unsigned short*)p; p += (size_t)32 * 1024 * 2;
  unsigned short* rhbuf = (unsigned short*)p; p += (size_t)32 * 1024 * 2;
  float* udf = out;  // ud aliases d_out's h region; see gemm epilogues

  hipMemsetAsync(bars, 0, SZ_BARS, stream);   // barrier counters must start at 0

  dim3 tb(32, 8);
  pack_bf<<<65536, 256, 0, stream>>>(x, xbf, 16384 * 1024);
  packT<<<dim3(96, 32), tb, 0, stream>>>(wgt, 6144, wxtT, 1024, 0);
  packT<<<dim3(64, 64), tb, 0, stream>>>(wgt + 3072, 6144, w1T, 2048, 0);
  packT<<<dim3(32, 32), tb, 0, stream>>>(wgt + (size_t)1024 * 6144 + 5120, 6144, w2T, 2048, 0);
  packT<<<dim3(32, 32), tb, 0, stream>>>(wgt + 5120, 6144, w2T, 2048, 1024);
  packT<<<dim3(64, 32), tb, 0, stream>>>(wgt + (size_t)1024 * 6144, 6144, wgT, 1024, 0);
  packT<<<dim3(32, 32), tb, 0, stream>>>(wgt + (size_t)1024 * 6144 + 2048, 6144, wcT, 1024, 0);

  // gates = bf16(x @ Wxt + bt)
  gemm_bt<0><<<dim3(24, 128), 256, 0, stream>>>(xbf, xbf, wxtT, 16384, 3072, 1024, 1024,
                                                bias, gates, nullptr, nullptr, nullptr, nullptr);

  // persistent recurrence: 512 steps, 2 groups x 64 blocks
  scan_pk<<<128, 256, 0, stream>>>(wgT, wcT, gates, ph, hb, rhbuf, htb,
                                   out + (size_t)16384 * 1024, bars);

  // grd = sigmoid(bd[:2048] + [x|ht] @ W1T^T) -> ud (f32, in d_out), rdx = bf16(rd*x)
  gemm_bt<1><<<dim3(16, 128), 256, 0, stream>>>(xbf, htb, w1T, 16384, 2048, 2048, 1024,
                                                bias + 3072, nullptr, x, udf, rdx, nullptr);
  // h = x + ud*(tanh(bd[2048:] + [ht|rdx] @ W2T^T) - x)
  gemm_bt<2><<<dim3(8, 128), 256, 0, stream>>>(htb, rdx, w2T, 16384, 1024, 2048, 1024,
                                               bias + 5120, nullptr, x, udf, nullptr, out);
}

// Round 4
// 3828.092 us; speedup vs baseline: 3.7750x; 1.0487x over previous
//
#include <hip/hip_runtime.h>
#include <stdint.h>

#define T_STEPS 512
#define GBLK 64   // blocks per scan group

typedef short short8 __attribute__((ext_vector_type(8)));
typedef float floatx4 __attribute__((ext_vector_type(4)));

__device__ __forceinline__ unsigned short f2bf(float f) {
  unsigned int u = __builtin_bit_cast(unsigned int, f);
  u = u + 0x7fff + ((u >> 16) & 1);   // round-to-nearest-even
  return (unsigned short)(u >> 16);
}
__device__ __forceinline__ float bf2f(unsigned short s) {
  unsigned int u = ((unsigned int)s) << 16;
  return __builtin_bit_cast(float, u);
}
__device__ __forceinline__ float sigm(float x) { return 1.f / (1.f + __expf(-x)); }
__device__ __forceinline__ float tanh_fast(float x) {
  float e2 = __expf(2.f * x);
  return 1.f - 2.f / (e2 + 1.f);
}

__device__ __forceinline__ void gload16(const void* g, const void* l) {
  __builtin_amdgcn_global_load_lds((const __attribute__((address_space(1))) unsigned int*)g,
                                   (__attribute__((address_space(3))) unsigned int*)l,
                                   16, 0, 0);
}

// ---------------------------------------------------------------------------
__global__ void pack_bf(const float* __restrict__ in, unsigned short* __restrict__ out, int n) {
  int i = blockIdx.x * 256 + threadIdx.x;
  if (i < n) out[i] = f2bf(in[i]);
}

__global__ void packT(const float* __restrict__ src, int srcStride,
                      unsigned short* __restrict__ dst, int dldk, int koff) {
  __shared__ float tile[32][33];
  int tx = threadIdx.x, ty = threadIdx.y;
  int e0 = blockIdx.x * 32, k0 = blockIdx.y * 32;
#pragma unroll
  for (int i = 0; i < 4; ++i)
    tile[ty + 8 * i][tx] = src[(size_t)(k0 + ty + 8 * i) * srcStride + e0 + tx];
  __syncthreads();
#pragma unroll
  for (int i = 0; i < 4; ++i)
    dst[(size_t)(e0 + ty + 8 * i) * dldk + koff + k0 + tx] = f2bf(tile[tx][ty + 8 * i]);
}

__global__ void sentinel(float* out, float v) { out[0] = v; }

// ---------------------------------------------------------------------------
// Big MFMA GEMM (unchanged, verified)
// ---------------------------------------------------------------------------
template <int EPI>
__global__ __launch_bounds__(256) void gemm_bt(
    const unsigned short* __restrict__ A0, const unsigned short* __restrict__ A1,
    const unsigned short* __restrict__ BT,
    int M, int Nn, int K, int KA0,
    const float* __restrict__ bias,
    unsigned short* __restrict__ out_bf,
    const float* __restrict__ xf,
    float* __restrict__ ud,
    unsigned short* __restrict__ rdx,
    float* __restrict__ outf) {
  __shared__ unsigned short At[128 * 32];
  __shared__ unsigned short Bt[128 * 32];
  const int tid = threadIdx.x;
  const int lane = tid & 63, wave = tid >> 6;
  const int wm = wave >> 1, wn = wave & 1;
  const int m0 = blockIdx.y * 128, n0 = blockIdx.x * 128;
  const int lr = lane & 15, lk = (lane >> 4) * 8;
  floatx4 acc[4][4] = {};

  for (int k0 = 0; k0 < K; k0 += 32) {
    const unsigned short* As;
    int kk;
    if (k0 < KA0) { As = A0 + (size_t)m0 * KA0 + k0; kk = KA0; }
    else          { As = A1 + (size_t)m0 * (K - KA0) + (k0 - KA0); kk = K - KA0; }
#pragma unroll
    for (int j = 0; j < 2; ++j) {
      int chunk = j * 256 + tid;
      int row = chunk >> 2, kc = chunk & 3;
      gload16(As + (size_t)row * kk + kc * 8, (const char*)At + chunk * 16);
    }
    const unsigned short* Bs = BT + (size_t)n0 * K + k0;
#pragma unroll
    for (int j = 0; j < 2; ++j) {
      int chunk = j * 256 + tid;
      int row = chunk >> 2, kc = chunk & 3;
      gload16(Bs + (size_t)row * K + kc * 8, (const char*)Bt + chunk * 16);
    }
    __syncthreads();
    short8 a[4], b[4];
#pragma unroll
    for (int i = 0; i < 4; ++i) a[i] = *(const short8*)(At + (wm * 64 + i * 16 + lr) * 32 + lk);
#pragma unroll
    for (int i = 0; i < 4; ++i) b[i] = *(const short8*)(Bt + (wn * 64 + i * 16 + lr) * 32 + lk);
#pragma unroll
    for (int i = 0; i < 4; ++i)
#pragma unroll
      for (int j = 0; j < 4; ++j)
        acc[i][j] = __builtin_amdgcn_mfma_f32_16x16x32_bf16(a[i], b[j], acc[i][j], 0, 0, 0);
    __syncthreads();
  }

#pragma unroll
  for (int i = 0; i < 4; ++i) {
#pragma unroll
    for (int j = 0; j < 4; ++j) {
      int col = n0 + wn * 64 + j * 16 + lr;
#pragma unroll
      for (int r = 0; r < 4; ++r) {
        int row = m0 + wm * 64 + i * 16 + (lane >> 4) * 4 + r;
        float v = acc[i][j][r];
        if constexpr (EPI == 0) {
          out_bf[(size_t)row * Nn + col] = f2bf(v + bias[col]);
        } else if constexpr (EPI == 1) {
          float s = sigm(v + bias[col]);
          if (col < 1024) {
            ud[(size_t)row * 1024 + col] = s;
          } else {
            size_t ix = (size_t)row * 1024 + (col - 1024);
            rdx[ix] = f2bf(s * xf[ix]);
          }
        } else {
          float hc = tanh_fast(v + bias[col]);
          size_t ix = (size_t)row * 1024 + col;
          float xv = xf[ix];
          outf[ix] = xv + ud[ix] * (hc - xv);   // ud aliases outf at same ix: safe
        }
      }
    }
  }
}

// ---------------------------------------------------------------------------
// Persistent scan, flag-barrier version.
// 128 blocks = 2 groups x 64. Group g owns batch rows [g*16,g*16+16); block b
// owns cols [b*16,b*16+16). Per-block flags (no atomic RMW): block stores its
// own flag (value = step-sense); pollers read all 64 flags lane-parallel.
// Step: [prefetch gates] poll flagB>=t+1 -> stage h -> r-GEMM -> store rh +
// flagA=t+1 -> u-GEMM (hides rh round-trip) -> poll flagA -> stage rh ->
// B-GEMM -> h update + store hb + flagB=t+2 -> htb history store (off-path).
// ---------------------------------------------------------------------------
__device__ __forceinline__ void wait_flags(unsigned int* f, unsigned int target) {
  if (threadIdx.x < 64) {   // wave 0 polls; lane i watches flag i
    unsigned int v = __hip_atomic_load(&f[threadIdx.x], __ATOMIC_RELAXED,
                                       __HIP_MEMORY_SCOPE_AGENT);
    int spins = 0;
    while (!__all(v >= target)) {
      if (++spins > (1 << 22)) break;   // safety valve: wrong answer > hang
      __builtin_amdgcn_s_sleep(1);
      v = __hip_atomic_load(&f[threadIdx.x], __ATOMIC_RELAXED,
                            __HIP_MEMORY_SCOPE_AGENT);
    }
    (void)__hip_atomic_load(&f[0], __ATOMIC_ACQUIRE, __HIP_MEMORY_SCOPE_AGENT); // inv
  }
  __syncthreads();
}

__global__ __launch_bounds__(256, 1) void scan_pk(
    const unsigned short* __restrict__ wgT,   // [2048][1024]
    const unsigned short* __restrict__ wcT,   // [1024][1024]
    const unsigned short* __restrict__ gates, // [32*512][3072]
    const float* __restrict__ ph,             // [32][1024]
    unsigned short* __restrict__ hb,          // [32][1024] broadcast h (bf16)
    unsigned short* __restrict__ rhbuf,       // [32][1024] broadcast r*h (bf16)
    unsigned short* __restrict__ htb,         // [32*512][1024]
    float* __restrict__ lastht,               // [32][1024]
    unsigned int* __restrict__ flags)         // [2 groups][2 kinds][64]
{
  __shared__ unsigned short Wg[32 * 1024];    // rows 0-15: u-cols, 16-31: r-cols
  __shared__ unsigned short Wc[16 * 1024];
  __shared__ unsigned short Stg[16 * 1024];   // h (phase A) / rh (phase B)
  __shared__ float Part[4][16][17];
  __shared__ float Ubuf[16][16];
  __shared__ float Hloc[16][16];
  __shared__ unsigned short Gbuf[3][16][16];  // gate slices: u, r, c

  const int tid = threadIdx.x;
  const int lane = tid & 63, wave = tid >> 6;
  const int lr = lane & 15, lq = lane >> 4;
  const int bid = blockIdx.x;
  const int g = bid >> 6, b = bid & 63;
  const int row0 = g * 16, col0 = b * 16;
  unsigned int* fA = flags + (g * 2 + 0) * 64;
  unsigned int* fB = flags + (g * 2 + 1) * 64;

  // ---- setup: weights -> LDS (source pre-swizzled: chunk ^= row&7) ----
#pragma unroll
  for (int i = 0; i < 16; ++i) {
    int p = i * 256 + tid;
    int wr = p >> 7, kcp = p & 127;
    int kc = kcp ^ (wr & 7);
    int grow = (wr < 16) ? (col0 + wr) : (1024 + col0 + (wr - 16));
    gload16(wgT + (size_t)grow * 1024 + kc * 8, (const char*)Wg + p * 16);
  }
#pragma unroll
  for (int i = 0; i < 8; ++i) {
    int p = i * 256 + tid;
    int wr = p >> 7, kcp = p & 127;
    int kc = kcp ^ (wr & 7);
    gload16(wcT + (size_t)(col0 + wr) * 1024 + kc * 8, (const char*)Wc + p * 16);
  }
  {
    int r = tid >> 4, c = tid & 15;
    float v = ph[(size_t)(row0 + r) * 1024 + col0 + c];
    Hloc[r][c] = v;
    __hip_atomic_store(&hb[(size_t)(row0 + r) * 1024 + col0 + c], f2bf(v),
                       __ATOMIC_RELAXED, __HIP_MEMORY_SCOPE_AGENT);
  }
  __syncthreads();                           // drains weight loads + hb stores
  if (tid == 0)
    __hip_atomic_store(&fB[b], 1u, __ATOMIC_RELAXED, __HIP_MEMORY_SCOPE_AGENT);

  for (int t = 0; t < T_STEPS; ++t) {
    // gate prefetch (independent of flags; overlaps poll)
    if (tid < 96) {
      int s = tid >> 5, row = (tid >> 1) & 15, half = tid & 1;
      int gcol = (s == 0) ? col0 : (s == 1) ? (1024 + col0) : (2048 + col0);
      gload16(gates + ((size_t)(row0 + row) * T_STEPS + t) * 3072 + gcol + half * 8,
              (const char*)&Gbuf[0][0][0] + tid * 16);
    }
    wait_flags(fB, t + 1);                   // all h(t) visible

    // ---- stage h ----
#pragma unroll
    for (int i = 0; i < 8; ++i) {
      int p = i * 256 + tid;
      int r = p >> 7, kcp = p & 127;
      int kc = kcp ^ (r & 7);
      gload16(hb + (size_t)(row0 + r) * 1024 + kc * 8, (const char*)Stg + p * 16);
    }
    __syncthreads();

    // ---- r-GEMM: 16x16, K=1024, 4-wave K-split ----
    {
      floatx4 acc = {};
#pragma unroll
      for (int ks8 = 0; ks8 < 8; ++ks8) {
        int kci = (wave * 8 + ks8) * 4 + lq;
        int sw = kci ^ (lr & 7);
        short8 av = *(const short8*)(Stg + lr * 1024 + sw * 8);
        short8 bv = *(const short8*)(Wg + (16 + lr) * 1024 + sw * 8);
        acc = __builtin_amdgcn_mfma_f32_16x16x32_bf16(av, bv, acc, 0, 0, 0);
      }
#pragma unroll
      for (int r = 0; r < 4; ++r) Part[wave][lq * 4 + r][lr] = acc[r];
    }
    __syncthreads();
    {
      int row = tid >> 4, c = tid & 15;
      float sum = Part[0][row][c] + Part[1][row][c] + Part[2][row][c] + Part[3][row][c];
      float sv = sigm(sum + bf2f(Gbuf[1][row][c]));
      __hip_atomic_store(&rhbuf[(size_t)(row0 + row) * 1024 + col0 + c],
                         f2bf(sv * Hloc[row][c]),
                         __ATOMIC_RELAXED, __HIP_MEMORY_SCOPE_AGENT);
    }
    __syncthreads();                         // drains rh stores
    if (tid == 0)
      __hip_atomic_store(&fA[b], (unsigned)(t + 1), __ATOMIC_RELAXED,
                         __HIP_MEMORY_SCOPE_AGENT);

    // ---- u-GEMM (hides the rh broadcast round-trip) ----
    {
      floatx4 acc = {};
#pragma unroll
      for (int ks8 = 0; ks8 < 8; ++ks8) {
        int kci = (wave * 8 + ks8) * 4 + lq;
        int sw = kci ^ (lr & 7);
        short8 av = *(const short8*)(Stg + lr * 1024 + sw * 8);
        short8 bv = *(const short8*)(Wg + lr * 1024 + sw * 8);
        acc = __builtin_amdgcn_mfma_f32_16x16x32_bf16(av, bv, acc, 0, 0, 0);
      }
#pragma unroll
      for (int r = 0; r < 4; ++r) Part[wave][lq * 4 + r][lr] = acc[r];
    }
    __syncthreads();
    {
      int row = tid >> 4, c = tid & 15;
      float sum = Part[0][row][c] + Part[1][row][c] + Part[2][row][c] + Part[3][row][c];
      Ubuf[row][c] = sigm(sum + bf2f(Gbuf[0][row][c]));
    }
    wait_flags(fA, t + 1);                   // all rh visible

    // ---- stage rh ----
#pragma unroll
    for (int i = 0; i < 8; ++i) {
      int p = i * 256 + tid;
      int r = p >> 7, kcp = p & 127;
      int kc = kcp ^ (r & 7);
      gload16(rhbuf + (size_t)(row0 + r) * 1024 + kc * 8, (const char*)Stg + p * 16);
    }
    __syncthreads();

    // ---- B-GEMM: hc = rh @ Whtc[cols], 4-wave K-split ----
    {
      floatx4 acc = {};
#pragma unroll
      for (int ks8 = 0; ks8 < 8; ++ks8) {
        int kci = (wave * 8 + ks8) * 4 + lq;
        int sw = kci ^ (lr & 7);
        short8 av = *(const short8*)(Stg + lr * 1024 + sw * 8);
        short8 bv = *(const short8*)(Wc + lr * 1024 + sw * 8);
        acc = __builtin_amdgcn_mfma_f32_16x16x32_bf16(av, bv, acc, 0, 0, 0);
      }
#pragma unroll
      for (int r = 0; r < 4; ++r) Part[wave][lq * 4 + r][lr] = acc[r];
    }
    __syncthreads();
    float hn;
    int row = tid >> 4, c = tid & 15;
    {
      float sum = Part[0][row][c] + Part[1][row][c] + Part[2][row][c] + Part[3][row][c];
      float hc = tanh_fast(sum + bf2f(Gbuf[2][row][c]));
      float h = Hloc[row][c], u = Ubuf[row][c];
      hn = h + u * (hc - h);
      Hloc[row][c] = hn;
      __hip_atomic_store(&hb[(size_t)(row0 + row) * 1024 + col0 + c], f2bf(hn),
                         __ATOMIC_RELAXED, __HIP_MEMORY_SCOPE_AGENT);
    }
    __syncthreads();                         // drains hb stores
    if (tid == 0)
      __hip_atomic_store(&fB[b], (unsigned)(t + 2), __ATOMIC_RELAXED,
                         __HIP_MEMORY_SCOPE_AGENT);
    // history store, off the critical path
    htb[((size_t)(row0 + row) * T_STEPS + t) * 1024 + col0 + c] = f2bf(hn);
    if (t == T_STEPS - 1) lastht[(size_t)(row0 + row) * 1024 + col0 + c] = hn;
  }
}

// ---------------------------------------------------------------------------
extern "C" void kernel_launch(void* const* d_in, const int* in_sizes, int n_in,
                              void* d_out, int out_size, void* d_ws, size_t ws_size,
                              hipStream_t stream) {
  const float* x    = (const float*)d_in[0];   // (32,512,1024)
  const float* ph   = (const float*)d_in[1];   // (32,1024)
  const float* wgt  = (const float*)d_in[2];   // (2048,6144)
  const float* bias = (const float*)d_in[3];   // (6144,)
  float* out = (float*)d_out;                  // h (16777216) + last_ht (32768)

  const size_t SZ_BARS  = 16384;                      // flags: 2*2*64*4 used
  const size_t SZ_XBF   = (size_t)16384 * 1024 * 2;
  const size_t SZ_GATES = (size_t)16384 * 3072 * 2;   // rdx aliases here after scan
  const size_t SZ_HTB   = (size_t)16384 * 1024 * 2;
  const size_t SZ_W     = ((size_t)3072 * 1024 + (size_t)2048 * 2048 +
                           (size_t)1024 * 2048 + (size_t)2048 * 1024 +
                           (size_t)1024 * 1024) * 2;
  const size_t SZ_SMALL = (size_t)(32 * 1024) * (2 + 2); // hb, rhbuf
  const size_t REQUIRED = SZ_BARS + SZ_XBF + SZ_GATES + SZ_HTB + SZ_W + SZ_SMALL;

  if (ws_size < REQUIRED) {
    sentinel<<<1, 1, 0, stream>>>(out, (float)ws_size);
    return;
  }

  char* p = (char*)d_ws;
  unsigned int* flags   = (unsigned int*)p;   p += SZ_BARS;
  unsigned short* xbf   = (unsigned short*)p; p += SZ_XBF;
  unsigned short* gates = (unsigned short*)p;
  unsigned short* rdx   = (unsigned short*)p; p += SZ_GATES;
  unsigned short* htb   = (unsigned short*)p; p += SZ_HTB;
  unsigned short* wxtT  = (unsigned short*)p; p += (size_t)3072 * 1024 * 2;
  unsigned short* w1T   = (unsigned short*)p; p += (size_t)2048 * 2048 * 2;
  unsigned short* w2T   = (unsigned short*)p; p += (size_t)1024 * 2048 * 2;
  unsigned short* wgT   = (unsigned short*)p; p += (size_t)2048 * 1024 * 2;
  unsigned short* wcT   = (unsigned short*)p; p += (size_t)1024 * 1024 * 2;
  unsigned short* hb    = (unsigned short*)p; p += (size_t)32 * 1024 * 2;
  unsigned short* rhbuf = (unsigned short*)p; p += (size_t)32 * 1024 * 2;
  float* udf = out;  // ud aliases d_out's h region; see gemm epilogues

  hipMemsetAsync(flags, 0, SZ_BARS, stream);  // step-sense flags start at 0

  dim3 tb(32, 8);
  pack_bf<<<65536, 256, 0, stream>>>(x, xbf, 16384 * 1024);
  packT<<<dim3(96, 32), tb, 0, stream>>>(wgt, 6144, wxtT, 1024, 0);
  packT<<<dim3(64, 64), tb, 0, stream>>>(wgt + 3072, 6144, w1T, 2048, 0);
  packT<<<dim3(32, 32), tb, 0, stream>>>(wgt + (size_t)1024 * 6144 + 5120, 6144, w2T, 2048, 0);
  packT<<<dim3(32, 32), tb, 0, stream>>>(wgt + 5120, 6144, w2T, 2048, 1024);
  packT<<<dim3(64, 32), tb, 0, stream>>>(wgt + (size_t)1024 * 6144, 6144, wgT, 1024, 0);
  packT<<<dim3(32, 32), tb, 0, stream>>>(wgt + (size_t)1024 * 6144 + 2048, 6144, wcT, 1024, 0);

  gemm_bt<0><<<dim3(24, 128), 256, 0, stream>>>(xbf, xbf, wxtT, 16384, 3072, 1024, 1024,
                                                bias, gates, nullptr, nullptr, nullptr, nullptr);

  scan_pk<<<128, 256, 0, stream>>>(wgT, wcT, gates, ph, hb, rhbuf, htb,
                                   out + (size_t)16384 * 1024, flags);

  gemm_bt<1><<<dim3(16, 128), 256, 0, stream>>>(xbf, htb, w1T, 16384, 2048, 2048, 1024,
                                                bias + 3072, nullptr, x, udf, rdx, nullptr);
  gemm_bt<2><<<dim3(8, 128), 256, 0, stream>>>(htb, rdx, w2T, 16384, 1024, 2048, 1024,
                                               bias + 5120, nullptr, x, udf, nullptr, out);
}